// Round 1
// baseline (60.556 us; speedup 1.0000x reference)
//
#include <hip/hip_runtime.h>

// QuantumPatchLayer collapses to a closed form:
//   RZ phases cancel in |amp|^2; CNOT ring permutes basis states:
//     b0' = b1^b2^b3, b1' = b0^b1, b2' = b0^b1^b2, b3' = b0^b1^b2^b3
//   Independent-bit product state => E[(-1)^(xor of S)] = prod_{i in S} cos(x_i)
//   => Z0 = c1*c2*c3, Z1 = c0*c1, Z2 = c0*c1*c2, Z3 = c0*c1*c2*c3
// Output (B, P*4) float32, contiguous [Z0,Z1,Z2,Z3] per patch -> float4 in/out.

__global__ void qpl_kernel(const float4* __restrict__ in,
                           float4* __restrict__ out, int n) {
    int i = blockIdx.x * blockDim.x + threadIdx.x;
    if (i >= n) return;
    float4 x = in[i];
    float c0 = __cosf(x.x);
    float c1 = __cosf(x.y);
    float c2 = __cosf(x.z);
    float c3 = __cosf(x.w);
    float4 o;
    float c12 = c1 * c2;
    o.x = c12 * c3;        // Z0
    o.y = c0 * c1;         // Z1
    o.z = c0 * c12;        // Z2
    o.w = o.z * c3;        // Z3
    out[i] = o;
}

extern "C" void kernel_launch(void* const* d_in, const int* in_sizes, int n_in,
                              void* d_out, int out_size, void* d_ws, size_t ws_size,
                              hipStream_t stream) {
    const float4* patches = (const float4*)d_in[0];  // (B,P,4) fp32, 4 per patch
    // d_in[1] = rz_params: provably unused (phases cancel in probabilities)
    float4* out = (float4*)d_out;                    // (B,P,4) fp32
    int n = in_sizes[0] / 4;                         // number of (batch,patch) pairs
    const int block = 256;
    int grid = (n + block - 1) / block;
    qpl_kernel<<<grid, block, 0, stream>>>(patches, out, n);
}